// Round 2
// baseline (855.778 us; speedup 1.0000x reference)
//
#include <hip/hip_runtime.h>
#include <cstdint>
#include <cstddef>

// Algebraic feature expansion: out[B,696] = concat(x[B,16],
//   all 2-subset products (120), all 3-subset products (560)).
// 730 MB out vs 17 MB in -> write-BW-bound; roofline = 116 us @ 6.3 TB/s.
//
// V3: register compute (V2) + wave-private LDS transpose, ZERO barriers.
// - block = 1 wave = 64 rows; each lane holds its row in 16 VGPRs
//   (all product indices constexpr -> pure v_mul, compiler CSEs pairs).
// - per pass: stage CHUNK=12 f4-cols x 64 rows into a wave-private slab
//   (ds_write_b128, conflict-free), s_waitcnt lgkmcnt(0) ONLY (same-wave
//   ordering; no s_barrier, no vmcnt(0) -> stores never waited on),
//   then drain with coalesced reads + plain stores.
// - small slab (12.2 KB) -> ~12 independent waves/CU -> continuous store flow.
// - plain (non-NT) stores: 192B runs merge into full 64B lines in L2;
//   NT would bypass L2 and risk partial-line RMW at HBM.

#define NCOLS       16
#define NOUT        696          // 16 + C(16,2)=120 + C(16,3)=560
#define F4_PER_ROW  174          // 696 / 4
#define THREADS     64           // one wave per block
#define CHUNK       12           // f4-cols staged per pass; 14 full + tail of 6
#define ROWPAD      65           // odd f4 stride -> structural-minimum reads

typedef float vfloat4 __attribute__((ext_vector_type(4)));

// Compile-time table: per output column, three 5-bit indices (16 = unused).
// Order matches itertools.combinations lexicographic order exactly.
struct Tab { uint32_t v[NOUT]; };
static constexpr Tab make_tab() {
    Tab T{};
    int n = 0;
    for (uint32_t c = 0; c < NCOLS; ++c)
        T.v[n++] = c | (16u << 8) | (16u << 16);
    for (uint32_t i = 0; i < NCOLS; ++i)
        for (uint32_t j = i + 1; j < NCOLS; ++j)
            T.v[n++] = i | (j << 8) | (16u << 16);
    for (uint32_t i = 0; i < NCOLS; ++i)
        for (uint32_t j = i + 1; j < NCOLS; ++j)
            for (uint32_t k = j + 1; k < NCOLS; ++k)
                T.v[n++] = i | (j << 8) | (k << 16);
    return T;
}
static constexpr Tab HT = make_tab();   // folded at compile time

// Product for output column COL from the register-resident row.
// constexpr indices -> x[] never leaves VGPRs (no scratch).
template<int COL>
__device__ __forceinline__ float prod_col(const float (&x)[NCOLS]) {
    constexpr uint32_t t = HT.v[COL];
    constexpr int a = t & 31;
    constexpr int b = (t >> 8) & 31;
    constexpr int c = (t >> 16) & 31;
    float r = x[a];
    if constexpr (b < NCOLS) r *= x[b];   // CSE'd across columns sharing (a,b)
    if constexpr (c < NCOLS) r *= x[c];
    return r;
}

// Compute f4 column C, ds_write_b128 into slab row (C-PBASE).
// st[c][lane]: lane-contiguous 16B -> conflict-free write.
template<int C, int END, int PBASE>
struct Emit {
    static __device__ __forceinline__ void run(const float (&x)[NCOLS],
                                               vfloat4 (&st)[CHUNK][ROWPAD],
                                               int lane) {
        vfloat4 o;
        o.x = prod_col<4 * C + 0>(x);
        o.y = prod_col<4 * C + 1>(x);
        o.z = prod_col<4 * C + 2>(x);
        o.w = prod_col<4 * C + 3>(x);
        st[C - PBASE][lane] = o;
        Emit<C + 1, END, PBASE>::run(x, st, lane);
    }
};
template<int END, int PBASE>
struct Emit<END, END, PBASE> {
    static __device__ __forceinline__ void run(const float (&)[NCOLS],
                                               vfloat4 (&)[CHUNK][ROWPAD], int) {}
};

// One pass: stage NC f4-cols, lgkm-wait, drain with coalesced stores.
// Drain read st[c4][rl]: lane stride 65 f4 = 260 words = 4 banks -> 8 lanes
// per bank-quad x 4 words = structural minimum for ds_read_b128 (no conflict).
template<int PBASE, int NC, bool FULL>
__device__ __forceinline__ void do_pass(const float (&x)[NCOLS],
                                        vfloat4 (&st)[CHUNK][ROWPAD],
                                        vfloat4* __restrict__ outv,
                                        int lane, int rows_left) {
    Emit<PBASE, PBASE + NC, PBASE>::run(x, st, lane);
    // Same-wave ds_write -> ds_read ordering; does NOT wait on global stores.
    asm volatile("s_waitcnt lgkmcnt(0)" ::: "memory");
#pragma unroll
    for (int i = 0; i < NC; ++i) {
        const int g  = i * THREADS + lane;      // g < NC*64
        const int rl = g / NC;                  // compile-time divisor magic
        const int c4 = g - rl * NC;
        const vfloat4 v = st[c4][rl];
        if (FULL || rl < rows_left)
            outv[(size_t)rl * F4_PER_ROW + PBASE + c4] = v;
    }
    // Reads complete before next pass overwrites the slab (same wave).
    asm volatile("s_waitcnt lgkmcnt(0)" ::: "memory");
}

template<int P, bool FULL>
struct Passes {
    static __device__ __forceinline__ void run(const float (&x)[NCOLS],
                                               vfloat4 (&st)[CHUNK][ROWPAD],
                                               vfloat4* __restrict__ outv,
                                               int lane, int rows_left) {
        constexpr int PBASE = P * CHUNK;
        constexpr int NC =
            (PBASE + CHUNK <= F4_PER_ROW) ? CHUNK : (F4_PER_ROW - PBASE);
        do_pass<PBASE, NC, FULL>(x, st, outv, lane, rows_left);
        if constexpr (PBASE + NC < F4_PER_ROW)
            Passes<P + 1, FULL>::run(x, st, outv, lane, rows_left);
    }
};

__global__ __launch_bounds__(THREADS) void algebraic_expand_kernel(
        const float* __restrict__ xg, float* __restrict__ out, int nrows) {
    __shared__ vfloat4 st[CHUNK][ROWPAD];   // 12*65*16 B = 12480 B

    const int lane = threadIdx.x;           // one wave: lane == tid
    const int r0   = blockIdx.x * THREADS;

    // Lane's row -> 16 VGPRs (4x b128, coalesced within the wave).
    float x[NCOLS];
    {
        const int row = r0 + lane;
        if (row < nrows) {
            const vfloat4* xr = (const vfloat4*)xg + (size_t)row * 4;
            const vfloat4 a = xr[0], b = xr[1], c = xr[2], d = xr[3];
            x[0]  = a.x; x[1]  = a.y; x[2]  = a.z; x[3]  = a.w;
            x[4]  = b.x; x[5]  = b.y; x[6]  = b.z; x[7]  = b.w;
            x[8]  = c.x; x[9]  = c.y; x[10] = c.z; x[11] = c.w;
            x[12] = d.x; x[13] = d.y; x[14] = d.z; x[15] = d.w;
        } else {
#pragma unroll
            for (int i = 0; i < NCOLS; ++i) x[i] = 0.0f;
        }
    }

    vfloat4* outv = (vfloat4*)out + (size_t)r0 * F4_PER_ROW;
    const int rem = nrows - r0;
    const int rows_left = rem < THREADS ? rem : THREADS;

    if (rows_left == THREADS) {
        // Hot path: every block is full when nrows % 64 == 0 (262144 is).
        Passes<0, true>::run(x, st, outv, lane, rows_left);
    } else {
        Passes<0, false>::run(x, st, outv, lane, rows_left);
    }
}

extern "C" void kernel_launch(void* const* d_in, const int* in_sizes, int n_in,
                              void* d_out, int out_size, void* d_ws, size_t ws_size,
                              hipStream_t stream) {
    const float* x = (const float*)d_in[0];
    float* out = (float*)d_out;
    const int nrows = in_sizes[0] / NCOLS;               // 262144
    const int blocks = (nrows + THREADS - 1) / THREADS;  // 4096
    algebraic_expand_kernel<<<blocks, THREADS, 0, stream>>>(x, out, nrows);
}